// Round 3
// baseline (345.670 us; speedup 1.0000x reference)
//
#include <hip/hip_runtime.h>

typedef __attribute__((ext_vector_type(8))) short bf16x8;
typedef __attribute__((ext_vector_type(4))) float f32x4;

#define Hh   16
#define Ll   680
#define Cc   1024
#define Bb   16
#define NSEG 10

__device__ __forceinline__ unsigned short f32_bf16(float f) {
  union { float f; unsigned int u; } x; x.f = f;
  unsigned int r = x.u + 0x7FFFu + ((x.u >> 16) & 1u);   // RNE
  return (unsigned short)(r >> 16);
}
__device__ __forceinline__ float bf16_f32(unsigned short u) {
  union { unsigned int u; float f; } x; x.u = ((unsigned int)u) << 16;
  return x.f;
}

__device__ __forceinline__ void async_copy16(const unsigned short* g, unsigned short* l) {
  __builtin_amdgcn_global_load_lds(
      (const __attribute__((address_space(1))) unsigned int*)g,
      (__attribute__((address_space(3))) unsigned int*)l, 16, 0, 0);
}

// ---------------- elementwise f32 -> bf16 cast ----------------
__global__ __launch_bounds__(256) void conv_kernel(const float* __restrict__ src,
                                                   unsigned short* __restrict__ dst, int n) {
  int i = (blockIdx.x * 256 + threadIdx.x) * 4;
  if (i + 3 < n) {
    float4 v = *reinterpret_cast<const float4*>(src + i);
    ushort4 o;
    o.x = f32_bf16(v.x); o.y = f32_bf16(v.y); o.z = f32_bf16(v.z); o.w = f32_bf16(v.w);
    *reinterpret_cast<ushort4*>(dst + i) = o;
  }
}

// bias = concat(q_bias, zeros, v_bias)
__global__ __launch_bounds__(256) void bias_kernel(const float* __restrict__ qb,
                                                   const float* __restrict__ vb,
                                                   float* __restrict__ out) {
  int i = blockIdx.x * 256 + threadIdx.x;
  if (i < 3072) {
    float v = 0.f;
    if (i < 1024) v = qb[i];
    else if (i >= 2048) v = vb[i - 2048];
    out[i] = v;
  }
}

// ---------------- B^T GEMM via global_load_lds + XOR-swizzled LDS ----------------
template <bool OUT_BF16>
__global__ __launch_bounds__(256) void gemm_bt(const unsigned short* __restrict__ A,
                                               const unsigned short* __restrict__ Bm,
                                               const float* __restrict__ bias,
                                               void* __restrict__ outp,
                                               int M, int N, int K) {
  __shared__ __align__(16) unsigned short As[128 * 64];
  __shared__ __align__(16) unsigned short Bs[128 * 64];
  const int t = threadIdx.x;
  const int lane = t & 63, w = t >> 6;
  const int col = lane & 15, quad = lane >> 4;
  const int wm = (w & 1) * 64, wn = (w >> 1) * 64;
  const int m0 = blockIdx.y * 128, n0 = blockIdx.x * 128;

  f32x4 acc[4][4];
#pragma unroll
  for (int i = 0; i < 4; ++i)
#pragma unroll
    for (int j = 0; j < 4; ++j)
#pragma unroll
      for (int r = 0; r < 4; ++r) acc[i][j][r] = 0.f;

  const int cbase = w * 256 + (t & 63);
  for (int k0 = 0; k0 < K; k0 += 64) {
    __syncthreads();
#pragma unroll
    for (int i = 0; i < 4; ++i) {
      int c = cbase + i * 64;
      int r = c >> 3;
      int part = (c & 7) ^ (r & 7);
      const unsigned short* ga = A + (size_t)(m0 + r) * K + k0 + part * 8;
      const unsigned short* gb = Bm + (size_t)(n0 + r) * K + k0 + part * 8;
      async_copy16(ga, As + (w * 256 + i * 64) * 8);
      async_copy16(gb, Bs + (w * 256 + i * 64) * 8);
    }
    __syncthreads();
#pragma unroll
    for (int kk = 0; kk < 64; kk += 32) {
      const int p = (kk >> 3) + quad;
      bf16x8 af[4], bfr[4];
#pragma unroll
      for (int mi = 0; mi < 4; ++mi) {
        int row = wm + mi * 16 + col;
        af[mi] = *reinterpret_cast<const bf16x8*>(&As[(row * 8 + (p ^ (col & 7))) * 8]);
      }
#pragma unroll
      for (int ni = 0; ni < 4; ++ni) {
        int row = wn + ni * 16 + col;
        bfr[ni] = *reinterpret_cast<const bf16x8*>(&Bs[(row * 8 + (p ^ (col & 7))) * 8]);
      }
#pragma unroll
      for (int mi = 0; mi < 4; ++mi)
#pragma unroll
        for (int ni = 0; ni < 4; ++ni)
          acc[mi][ni] = __builtin_amdgcn_mfma_f32_16x16x32_bf16(af[mi], bfr[ni], acc[mi][ni], 0, 0, 0);
    }
  }
#pragma unroll
  for (int mi = 0; mi < 4; ++mi) {
#pragma unroll
    for (int ni = 0; ni < 4; ++ni) {
      int gn = n0 + wn + ni * 16 + col;
      float bv = bias[gn];
#pragma unroll
      for (int r = 0; r < 4; ++r) {
        int gm = m0 + wm + mi * 16 + quad * 4 + r;
        float v = acc[mi][ni][r] + bv;
        size_t off = (size_t)gm * N + gn;
        if (OUT_BF16) ((unsigned short*)outp)[off] = f32_bf16(v);
        else ((float*)outp)[off] = v;
      }
    }
  }
}

// ---------------- attention v3: 4096 blocks, 1 Q-tile/wave, K chunked @128 ----------------
// Work table (patch_nums are compile-time constants): 16 blocks per (b,h).
__device__ __constant__ int c_seg[16]   = {0,1,2,3,4,5,6,7,7,8,8,8,9,9,9,9};
__device__ __constant__ int c_tile0[16] = {0,0,0,0,0,0,0,0,4,0,4,8,0,4,8,12};
__device__ __constant__ int c_start[NSEG] = {0,1,5,14,30,55,91,155,255,424};
__device__ __constant__ int c_len[NSEG]   = {1,4,9,16,25,36,64,100,169,256};

__global__ __launch_bounds__(256) void attn_kernel(const unsigned short* __restrict__ qkv,
                                                   const float* __restrict__ slog,
                                                   unsigned short* __restrict__ outb) {
  __shared__ __align__(16) unsigned short Ks[128 * 64];   // swizzled: row*8 + (c ^ (row&7))
  __shared__ __align__(16) unsigned short Vt[64 * 128];   // swizzled: d*16 + ((c&8)|((c&7)^(d&7)))
  __shared__ __align__(16) unsigned short Ps[4 * 16 * 132];

  const int t = threadIdx.x;
  const int lane = t & 63, w = t >> 6;
  const int col = lane & 15, quad = lane >> 4;
  const int bh = blockIdx.x >> 4, wi = blockIdx.x & 15;
  const int b = bh >> 4, h = bh & 15;
  const int seg = c_seg[wi];
  const int start = c_start[seg], ln = c_len[seg];
  const int njt = (ln + 15) >> 4;
  const int nchunk = (njt + 7) >> 3;
  const int qt = c_tile0[wi] + w;
  const bool qvalid = qt < njt;
  const float smul = __expf(fminf(slog[h], 4.6051701859880914f));

  // ---- Q fragment load + in-register l2norm*scale (row qi always within the b-slab) ----
  const int qi = qt * 16 + col;
  const unsigned short* qrow = qkv + ((size_t)(b * Ll + start + qi) * 3) * Cc + h * 64;
  bf16x8 qf0 = *reinterpret_cast<const bf16x8*>(qrow + quad * 8);
  bf16x8 qf1 = *reinterpret_cast<const bf16x8*>(qrow + 32 + quad * 8);
  {
    float ss = 0.f;
#pragma unroll
    for (int e = 0; e < 8; ++e) {
      float f0 = bf16_f32((unsigned short)qf0[e]), f1 = bf16_f32((unsigned short)qf1[e]);
      ss += f0 * f0 + f1 * f1;
    }
    ss += __shfl_xor(ss, 16);
    ss += __shfl_xor(ss, 32);
    const float qsc = smul / fmaxf(sqrtf(ss), 1e-12f);
#pragma unroll
    for (int e = 0; e < 8; ++e) {
      qf0[e] = (short)f32_bf16(bf16_f32((unsigned short)qf0[e]) * qsc);
      qf1[e] = (short)f32_bf16(bf16_f32((unsigned short)qf1[e]) * qsc);
    }
  }

  f32x4 o[4];
#pragma unroll
  for (int nt = 0; nt < 4; ++nt)
#pragma unroll
    for (int r = 0; r < 4; ++r) o[nt][r] = 0.f;
  float m4[4] = {-1e30f, -1e30f, -1e30f, -1e30f};
  float l4[4] = {0.f, 0.f, 0.f, 0.f};

  for (int ch = 0; ch < nchunk; ++ch) {
    const int jbase = ch * 128;
    const int jtc = njt - ch * 8 > 8 ? 8 : njt - ch * 8;   // valid j-tiles this chunk
    const int jtcp = (jtc + 1) & ~1;                        // padded to even
    __syncthreads();   // previous chunk's LDS reads done

    // ---- stage raw K (128 rows x 64d) via global_load_lds, XOR-swizzled ----
#pragma unroll
    for (int i = 0; i < 4; ++i) {
      int cl = i * 256 + w * 64 + lane;
      int jr = cl >> 3, pos = cl & 7;
      int c = pos ^ (jr & 7);
      const unsigned short* g =
          qkv + ((size_t)(b * Ll + start + jbase + jr) * 3 + 1) * Cc + h * 64 + c * 8;
      async_copy16(g, Ks + (i * 256 + w * 64) * 8);
    }
    // ---- stage V transposed: vector global read, scalar LDS scatter ----
    {
      const int j = t >> 1, half = t & 1;
      const unsigned short* vrow =
          qkv + ((size_t)(b * Ll + start + jbase + j) * 3 + 2) * Cc + h * 64 + half * 32;
      uint4 vv[4];
#pragma unroll
      for (int i = 0; i < 4; ++i) vv[i] = *reinterpret_cast<const uint4*>(vrow + i * 8);
      const int cj = j >> 3, jo = j & 7;
#pragma unroll
      for (int i = 0; i < 4; ++i) {
        const unsigned short* u = (const unsigned short*)&vv[i];
#pragma unroll
        for (int e = 0; e < 8; ++e) {
          int d = half * 32 + i * 8 + e;
          int pos = (cj & 8) | ((cj & 7) ^ (d & 7));
          Vt[(d * 16 + pos) * 8 + jo] = u[e];
        }
      }
    }
    __syncthreads();

    // ---- normalize K rows in LDS (2 threads/row, vectorized b128 RMW) ----
    {
      const int jr = t >> 1, half = t & 1;
      bf16x8 kv[4];
      float ss = 0.f;
#pragma unroll
      for (int i = 0; i < 4; ++i) {
        int c = half * 4 + i;
        kv[i] = *reinterpret_cast<const bf16x8*>(&Ks[(jr * 8 + (c ^ (jr & 7))) * 8]);
#pragma unroll
        for (int e = 0; e < 8; ++e) { float f = bf16_f32((unsigned short)kv[i][e]); ss += f * f; }
      }
      ss += __shfl_xor(ss, 1);
      float sc = 1.f / fmaxf(sqrtf(ss), 1e-12f);
#pragma unroll
      for (int i = 0; i < 4; ++i) {
        int c = half * 4 + i;
        bf16x8 ov;
#pragma unroll
        for (int e = 0; e < 8; ++e) ov[e] = (short)f32_bf16(bf16_f32((unsigned short)kv[i][e]) * sc);
        *reinterpret_cast<bf16x8*>(&Ks[(jr * 8 + (c ^ (jr & 7))) * 8]) = ov;
      }
    }
    __syncthreads();

    // ---- S = Q K^T for this wave's tile over the chunk ----
    f32x4 sf[8];
#pragma unroll
    for (int jt = 0; jt < 8; ++jt) {
      if (jt >= jtcp) continue;
      f32x4 s;
#pragma unroll
      for (int r = 0; r < 4; ++r) s[r] = 0.f;
      if (jt < jtc) {
        int jrow = jt * 16 + col;
        bf16x8 k0 = *reinterpret_cast<const bf16x8*>(&Ks[(jrow * 8 + (quad ^ (col & 7))) * 8]);
        bf16x8 k1 = *reinterpret_cast<const bf16x8*>(&Ks[(jrow * 8 + ((4 + quad) ^ (col & 7))) * 8]);
        s = __builtin_amdgcn_mfma_f32_16x16x32_bf16(qf0, k0, s, 0, 0, 0);
        s = __builtin_amdgcn_mfma_f32_16x16x32_bf16(qf1, k1, s, 0, 0, 0);
      }
      if (jbase + jt * 16 + col >= ln) {
#pragma unroll
        for (int r = 0; r < 4; ++r) s[r] = -1e30f;
      }
      sf[jt] = s;
    }
    // ---- online softmax update ----
    float mc[4];
#pragma unroll
    for (int r = 0; r < 4; ++r) mc[r] = sf[0][r];
#pragma unroll
    for (int jt = 1; jt < 8; ++jt) {
      if (jt >= jtcp) continue;
#pragma unroll
      for (int r = 0; r < 4; ++r) mc[r] = fmaxf(mc[r], sf[jt][r]);
    }
#pragma unroll
    for (int mask = 1; mask <= 8; mask <<= 1)
#pragma unroll
      for (int r = 0; r < 4; ++r) mc[r] = fmaxf(mc[r], __shfl_xor(mc[r], mask));
    float alpha[4];
#pragma unroll
    for (int r = 0; r < 4; ++r) {
      float mn = fmaxf(m4[r], mc[r]);
      alpha[r] = __expf(m4[r] - mn);
      m4[r] = mn;
    }
    float ls[4] = {0.f, 0.f, 0.f, 0.f};
#pragma unroll
    for (int jt = 0; jt < 8; ++jt) {
      if (jt >= jtcp) continue;
#pragma unroll
      for (int r = 0; r < 4; ++r) {
        float pv = __expf(sf[jt][r] - m4[r]);
        ls[r] += pv;
        Ps[(w * 16 + quad * 4 + r) * 132 + jt * 16 + col] = f32_bf16(pv);
      }
    }
#pragma unroll
    for (int mask = 1; mask <= 8; mask <<= 1)
#pragma unroll
      for (int r = 0; r < 4; ++r) ls[r] += __shfl_xor(ls[r], mask);
#pragma unroll
    for (int r = 0; r < 4; ++r) l4[r] = l4[r] * alpha[r] + ls[r];
#pragma unroll
    for (int nt = 0; nt < 4; ++nt)
#pragma unroll
      for (int r = 0; r < 4; ++r) o[nt][r] *= alpha[r];

    // ---- O += P V (A=Ps per-wave, B=Vt swizzled; no barrier needed before reads) ----
#pragma unroll
    for (int kk2 = 0; kk2 < 4; ++kk2) {
      if (kk2 >= (jtcp >> 1)) continue;
      bf16x8 pf = *reinterpret_cast<const bf16x8*>(&Ps[(w * 16 + col) * 132 + kk2 * 32 + quad * 8]);
#pragma unroll
      for (int nt = 0; nt < 4; ++nt) {
        int d = nt * 16 + col;
        int c2 = kk2 * 4 + quad;
        int pos = (c2 & 8) | ((c2 & 7) ^ (d & 7));
        bf16x8 vf = *reinterpret_cast<const bf16x8*>(&Vt[(d * 16 + pos) * 8]);
        o[nt] = __builtin_amdgcn_mfma_f32_16x16x32_bf16(pf, vf, o[nt], 0, 0, 0);
      }
    }
  }

  if (qvalid) {
    float inv[4];
#pragma unroll
    for (int r = 0; r < 4; ++r) inv[r] = 1.f / l4[r];
#pragma unroll
    for (int nt = 0; nt < 4; ++nt)
#pragma unroll
      for (int r = 0; r < 4; ++r) {
        int ri = qt * 16 + quad * 4 + r;
        if (ri < ln) {
          size_t off = ((size_t)b * Ll + start + ri) * Cc + h * 64 + nt * 16 + col;
          outb[off] = f32_bf16(o[nt][r] * inv[r]);
        }
      }
  }
}

extern "C" void kernel_launch(void* const* d_in, const int* in_sizes, int n_in,
                              void* d_out, int out_size, void* d_ws, size_t ws_size,
                              hipStream_t stream) {
  const float* x     = (const float*)d_in[0];
  const float* wqkv  = (const float*)d_in[2];
  const float* qbias = (const float*)d_in[3];
  const float* vbias = (const float*)d_in[4];
  const float* slog  = (const float*)d_in[5];
  const float* wproj = (const float*)d_in[6];
  const float* pbias = (const float*)d_in[7];
  float* out = (float*)d_out;

  const size_t nX   = (size_t)Bb * Ll * Cc;      // 11,141,120
  const size_t nWq  = (size_t)3 * Cc * Cc;       // 3,145,728
  const size_t nWp  = (size_t)Cc * Cc;           // 1,048,576
  const size_t nQKV = (size_t)Bb * Ll * 3 * Cc;  // 33,423,360

  char* p = (char*)d_ws;
  unsigned short* xb     = (unsigned short*)p;  p += nX * 2;
  unsigned short* wqkvb  = (unsigned short*)p;  p += nWq * 2;
  unsigned short* wprojb = (unsigned short*)p;  p += nWp * 2;
  float*          bqkv   = (float*)p;           p += 3072 * 4;
  unsigned short* qkv    = (unsigned short*)p;  p += nQKV * 2;
  unsigned short* attn   = xb;  // reuse: xb dead after QKV GEMM

  conv_kernel<<<(int)(nX / 1024), 256, 0, stream>>>(x, xb, (int)nX);
  conv_kernel<<<(int)(nWq / 1024), 256, 0, stream>>>(wqkv, wqkvb, (int)nWq);
  conv_kernel<<<(int)(nWp / 1024), 256, 0, stream>>>(wproj, wprojb, (int)nWp);
  bias_kernel<<<12, 256, 0, stream>>>(qbias, vbias, bqkv);

  gemm_bt<true><<<dim3(24, 85), 256, 0, stream>>>(xb, wqkvb, bqkv, qkv, 10880, 3072, 1024);
  attn_kernel<<<Bb * Hh * 16, 256, 0, stream>>>(qkv, slog, attn);
  gemm_bt<false><<<dim3(8, 85), 256, 0, stream>>>(attn, wprojb, pbias, out, 10880, 1024, 1024);
}

// Round 5
// 341.882 us; speedup vs baseline: 1.0111x; 1.0111x over previous
//
#include <hip/hip_runtime.h>

typedef __attribute__((ext_vector_type(8))) short bf16x8;
typedef __attribute__((ext_vector_type(4))) float f32x4;

#define Hh   16
#define Ll   680
#define Cc   1024
#define Bb   16
#define NSEG 10
#define LPAD 720   // padded per-segment V length (each segment start 8-aligned)

__device__ __forceinline__ unsigned short f32_bf16(float f) {
  union { float f; unsigned int u; } x; x.f = f;
  unsigned int r = x.u + 0x7FFFu + ((x.u >> 16) & 1u);   // RNE
  return (unsigned short)(r >> 16);
}
__device__ __forceinline__ float bf16_f32(unsigned short u) {
  union { unsigned int u; float f; } x; x.u = ((unsigned int)u) << 16;
  return x.f;
}

__device__ __forceinline__ void async_copy16(const unsigned short* g, unsigned short* l) {
  __builtin_amdgcn_global_load_lds(
      (const __attribute__((address_space(1))) unsigned int*)g,
      (__attribute__((address_space(3))) unsigned int*)l, 16, 0, 0);
}

// segment tables (patch_nums are compile-time constants)
__device__ __constant__ int c_start2[11] = {0,1,5,14,30,55,91,155,255,424,680};
__device__ __constant__ int c_ps[NSEG]   = {0,8,16,32,48,80,120,184,288,464};
__device__ __constant__ int c_seg[16]    = {0,1,2,3,4,5,6,7,7,8,8,8,9,9,9,9};
__device__ __constant__ int c_tile0[16]  = {0,0,0,0,0,0,0,0,4,0,4,8,0,4,8,12};
__device__ __constant__ int c_len[NSEG]  = {1,4,9,16,25,36,64,100,169,256};

// ---------------- elementwise f32 -> bf16 cast ----------------
__global__ __launch_bounds__(256) void conv_kernel(const float* __restrict__ src,
                                                   unsigned short* __restrict__ dst, int n) {
  int i = (blockIdx.x * 256 + threadIdx.x) * 4;
  if (i + 3 < n) {
    float4 v = *reinterpret_cast<const float4*>(src + i);
    ushort4 o;
    o.x = f32_bf16(v.x); o.y = f32_bf16(v.y); o.z = f32_bf16(v.z); o.w = f32_bf16(v.w);
    *reinterpret_cast<ushort4*>(dst + i) = o;
  }
}

// ---------------- QKV GEMM with fused epilogue ----------------
// A: 10880x1024, Bm: 3072x1024 (B^T). Per 128-n tile: one field, two heads.
// q -> (B,H,L,D) +bias ; k -> (B,H,L,D) l2-normalized ; v -> (B,H,D,LPAD) +bias, transposed.
__global__ __launch_bounds__(256) void gemm_qkv(const unsigned short* __restrict__ A,
                                                const unsigned short* __restrict__ Bm,
                                                const float* __restrict__ qb,
                                                const float* __restrict__ vb,
                                                unsigned short* __restrict__ qn,
                                                unsigned short* __restrict__ kn,
                                                unsigned short* __restrict__ vtb) {
  constexpr int K = 1024;
  __shared__ __align__(16) unsigned short As[128 * 64];
  __shared__ __align__(16) unsigned short Bs[128 * 64];
  const int t = threadIdx.x;
  const int lane = t & 63, w = t >> 6;
  const int col = lane & 15, quad = lane >> 4;
  const int wm = (w & 1) * 64, wn = (w >> 1) * 64;
  const int m0 = blockIdx.y * 128, n0 = blockIdx.x * 128;

  f32x4 acc[4][4];
#pragma unroll
  for (int i = 0; i < 4; ++i)
#pragma unroll
    for (int j = 0; j < 4; ++j)
#pragma unroll
      for (int r = 0; r < 4; ++r) acc[i][j][r] = 0.f;

  const int cbase = w * 256 + lane;
  for (int k0 = 0; k0 < K; k0 += 64) {
    __syncthreads();
#pragma unroll
    for (int i = 0; i < 4; ++i) {
      int c = cbase + i * 64;
      int r = c >> 3;
      int part = (c & 7) ^ (r & 7);
      async_copy16(A + (size_t)(m0 + r) * K + k0 + part * 8, As + (w * 256 + i * 64) * 8);
      async_copy16(Bm + (size_t)(n0 + r) * K + k0 + part * 8, Bs + (w * 256 + i * 64) * 8);
    }
    __syncthreads();
#pragma unroll
    for (int kk = 0; kk < 64; kk += 32) {
      const int p = (kk >> 3) + quad;
      bf16x8 af[4], bfr[4];
#pragma unroll
      for (int mi = 0; mi < 4; ++mi) {
        int row = wm + mi * 16 + col;
        af[mi] = *reinterpret_cast<const bf16x8*>(&As[(row * 8 + (p ^ (col & 7))) * 8]);
      }
#pragma unroll
      for (int ni = 0; ni < 4; ++ni) {
        int row = wn + ni * 16 + col;
        bfr[ni] = *reinterpret_cast<const bf16x8*>(&Bs[(row * 8 + (p ^ (col & 7))) * 8]);
      }
#pragma unroll
      for (int mi = 0; mi < 4; ++mi)
#pragma unroll
        for (int ni = 0; ni < 4; ++ni)
          acc[mi][ni] = __builtin_amdgcn_mfma_f32_16x16x32_bf16(af[mi], bfr[ni], acc[mi][ni], 0, 0, 0);
    }
  }

  const int nbase = n0 + wn;
  const int field = nbase >> 10;          // wave-uniform
  const int h = (nbase >> 6) & 15;

  if (field < 2) {
    float scl[4][4];
    if (field == 1) {                     // k: per-row 1/||k|| across the 16 col-lanes (full d=64)
#pragma unroll
      for (int mi = 0; mi < 4; ++mi)
#pragma unroll
        for (int r = 0; r < 4; ++r) {
          float s = 0.f;
#pragma unroll
          for (int ni = 0; ni < 4; ++ni) s += acc[mi][ni][r] * acc[mi][ni][r];
          s += __shfl_xor(s, 1); s += __shfl_xor(s, 2);
          s += __shfl_xor(s, 4); s += __shfl_xor(s, 8);
          scl[mi][r] = 1.f / fmaxf(sqrtf(s), 1e-12f);
        }
    }
    unsigned short* dst0 = (field == 0) ? qn : kn;
#pragma unroll
    for (int ni = 0; ni < 4; ++ni) {
      const int d = ni * 16 + col;
      const float bv = (field == 0) ? qb[h * 64 + d] : 0.f;
#pragma unroll
      for (int mi = 0; mi < 4; ++mi)
#pragma unroll
        for (int r = 0; r < 4; ++r) {
          int gm = m0 + wm + mi * 16 + quad * 4 + r;
          int b = gm / 680, l = gm - b * 680;
          float v = (field == 0) ? (acc[mi][ni][r] + bv) : (acc[mi][ni][r] * scl[mi][r]);
          dst0[((size_t)(b * Hh + h) * Ll + l) * 64 + d] = f32_bf16(v);
        }
    }
  } else {                                // v: transposed, segment-padded
#pragma unroll
    for (int mi = 0; mi < 4; ++mi) {
      int pl4[4], bb4[4];
#pragma unroll
      for (int r = 0; r < 4; ++r) {
        int gm = m0 + wm + mi * 16 + quad * 4 + r;
        int b = gm / 680, l = gm - b * 680;
        int seg = 0;
#pragma unroll
        for (int s2 = 1; s2 < NSEG; ++s2) seg += (l >= c_start2[s2]) ? 1 : 0;
        pl4[r] = l - c_start2[seg] + c_ps[seg];
        bb4[r] = b;
      }
#pragma unroll
      for (int ni = 0; ni < 4; ++ni) {
        const int d = ni * 16 + col;
        const float bv = vb[h * 64 + d];
#pragma unroll
        for (int r = 0; r < 4; ++r)
          vtb[((size_t)(bb4[r] * Hh + h) * 64 + d) * LPAD + pl4[r]] =
              f32_bf16(acc[mi][ni][r] + bv);
      }
    }
  }
}

// ---------------- plain B^T GEMM (proj), f32 out ----------------
__global__ __launch_bounds__(256) void gemm_bt(const unsigned short* __restrict__ A,
                                               const unsigned short* __restrict__ Bm,
                                               const float* __restrict__ bias,
                                               float* __restrict__ outp,
                                               int M, int N, int K) {
  __shared__ __align__(16) unsigned short As[128 * 64];
  __shared__ __align__(16) unsigned short Bs[128 * 64];
  const int t = threadIdx.x;
  const int lane = t & 63, w = t >> 6;
  const int col = lane & 15, quad = lane >> 4;
  const int wm = (w & 1) * 64, wn = (w >> 1) * 64;
  const int m0 = blockIdx.y * 128, n0 = blockIdx.x * 128;

  f32x4 acc[4][4];
#pragma unroll
  for (int i = 0; i < 4; ++i)
#pragma unroll
    for (int j = 0; j < 4; ++j)
#pragma unroll
      for (int r = 0; r < 4; ++r) acc[i][j][r] = 0.f;

  const int cbase = w * 256 + lane;
  for (int k0 = 0; k0 < K; k0 += 64) {
    __syncthreads();
#pragma unroll
    for (int i = 0; i < 4; ++i) {
      int c = cbase + i * 64;
      int r = c >> 3;
      int part = (c & 7) ^ (r & 7);
      async_copy16(A + (size_t)(m0 + r) * K + k0 + part * 8, As + (w * 256 + i * 64) * 8);
      async_copy16(Bm + (size_t)(n0 + r) * K + k0 + part * 8, Bs + (w * 256 + i * 64) * 8);
    }
    __syncthreads();
#pragma unroll
    for (int kk = 0; kk < 64; kk += 32) {
      const int p = (kk >> 3) + quad;
      bf16x8 af[4], bfr[4];
#pragma unroll
      for (int mi = 0; mi < 4; ++mi) {
        int row = wm + mi * 16 + col;
        af[mi] = *reinterpret_cast<const bf16x8*>(&As[(row * 8 + (p ^ (col & 7))) * 8]);
      }
#pragma unroll
      for (int ni = 0; ni < 4; ++ni) {
        int row = wn + ni * 16 + col;
        bfr[ni] = *reinterpret_cast<const bf16x8*>(&Bs[(row * 8 + (p ^ (col & 7))) * 8]);
      }
#pragma unroll
      for (int mi = 0; mi < 4; ++mi)
#pragma unroll
        for (int ni = 0; ni < 4; ++ni)
          acc[mi][ni] = __builtin_amdgcn_mfma_f32_16x16x32_bf16(af[mi], bfr[ni], acc[mi][ni], 0, 0, 0);
    }
  }
#pragma unroll
  for (int mi = 0; mi < 4; ++mi)
#pragma unroll
    for (int ni = 0; ni < 4; ++ni) {
      int gn = n0 + wn + ni * 16 + col;
      float bv = bias[gn];
#pragma unroll
      for (int r = 0; r < 4; ++r) {
        int gm = m0 + wm + mi * 16 + quad * 4 + r;
        outp[(size_t)gm * N + gn] = acc[mi][ni][r] + bv;
      }
    }
}

// ---------------- attention v4b: pure dataflow (prep fused into GEMM epilogue) ----------------
// 4096 blocks, 1 Q-tile/wave, K chunked @128; K and V^T staged via global_load_lds,
// XOR-swizzled; no normalize phase, no scatter; one barrier pair per chunk.
__global__ __launch_bounds__(256) void attn_kernel(const unsigned short* __restrict__ qn,
                                                   const unsigned short* __restrict__ kn,
                                                   const unsigned short* __restrict__ vtb,
                                                   const float* __restrict__ slog,
                                                   unsigned short* __restrict__ outb) {
  __shared__ __align__(16) unsigned short Ks[128 * 64];   // chunk(row,cc) at row*8 + (cc^(row&7))
  __shared__ __align__(16) unsigned short Vs[64 * 128];   // chunk(d,jc)  at d*16 + (jc^(d&15))
  __shared__ __align__(16) unsigned short Ps[4 * 16 * 132];

  const int t = threadIdx.x;
  const int lane = t & 63, w = t >> 6;
  const int col = lane & 15, quad = lane >> 4;
  const int bh = blockIdx.x >> 4, wi = blockIdx.x & 15;
  const int h = bh & 15;
  const int seg = c_seg[wi];
  const int start = c_start2[seg], ln = c_len[seg], ps = c_ps[seg];
  const int njt = (ln + 15) >> 4;
  const int nchunk = (njt + 7) >> 3;
  const int qt = c_tile0[wi] + w;
  const bool qvalid = qt < njt;
  const float smul = __expf(fminf(slog[h], 4.6051701859880914f));

  // ---- Q fragment + in-register l2norm*scale ----
  const int qi = qt * 16 + col;
  const unsigned short* qrow = qn + ((size_t)bh * Ll + start + qi) * 64;
  bf16x8 qf0 = *reinterpret_cast<const bf16x8*>(qrow + quad * 8);
  bf16x8 qf1 = *reinterpret_cast<const bf16x8*>(qrow + 32 + quad * 8);
  {
    float ss = 0.f;
#pragma unroll
    for (int e = 0; e < 8; ++e) {
      float f0 = bf16_f32((unsigned short)qf0[e]), f1 = bf16_f32((unsigned short)qf1[e]);
      ss += f0 * f0 + f1 * f1;
    }
    ss += __shfl_xor(ss, 16);
    ss += __shfl_xor(ss, 32);
    const float qsc = smul / fmaxf(sqrtf(ss), 1e-12f);
#pragma unroll
    for (int e = 0; e < 8; ++e) {
      qf0[e] = (short)f32_bf16(bf16_f32((unsigned short)qf0[e]) * qsc);
      qf1[e] = (short)f32_bf16(bf16_f32((unsigned short)qf1[e]) * qsc);
    }
  }

  f32x4 o[4];
#pragma unroll
  for (int nt = 0; nt < 4; ++nt)
#pragma unroll
    for (int r = 0; r < 4; ++r) o[nt][r] = 0.f;
  float m4[4] = {-1e30f, -1e30f, -1e30f, -1e30f};
  float l4[4] = {0.f, 0.f, 0.f, 0.f};

  for (int ch = 0; ch < nchunk; ++ch) {
    const int jbase = ch * 128;
    const int jtc = (njt - ch * 8 > 8) ? 8 : (njt - ch * 8);
    const int jtcp = (jtc + 1) & ~1;
    __syncthreads();   // previous chunk's LDS reads done

    // ---- stage K rows (128 x 64d): chunk grid 128x8 ----
#pragma unroll
    for (int i = 0; i < 4; ++i) {
      int c = i * 256 + w * 64 + lane;
      int jr = c >> 3, pos = c & 7;
      int cc = pos ^ (jr & 7);
      async_copy16(kn + ((size_t)bh * Ll + start + jbase + jr) * 64 + cc * 8,
                   Ks + (i * 256 + w * 64) * 8);
    }
    // ---- stage V^T (64d x 128j): chunk grid 64x16 ----
#pragma unroll
    for (int i = 0; i < 4; ++i) {
      int c = i * 256 + w * 64 + lane;
      int d = c >> 4, pos = c & 15;
      int jc = pos ^ (d & 15);
      async_copy16(vtb + ((size_t)bh * 64 + d) * LPAD + ps + jbase + jc * 8,
                   Vs + (i * 256 + w * 64) * 8);
    }
    __syncthreads();

    // ---- S = Q K^T ----
    f32x4 sf[8];
#pragma unroll
    for (int jt = 0; jt < 8; ++jt) {
      if (jt >= jtcp) continue;
      f32x4 s;
#pragma unroll
      for (int r = 0; r < 4; ++r) s[r] = 0.f;
      if (jt < jtc) {
        int jrow = jt * 16 + col;
        bf16x8 k0 = *reinterpret_cast<const bf16x8*>(&Ks[(jrow * 8 + (quad ^ (jrow & 7))) * 8]);
        bf16x8 k1 = *reinterpret_cast<const bf16x8*>(&Ks[(jrow * 8 + ((4 + quad) ^ (jrow & 7))) * 8]);
        s = __builtin_amdgcn_mfma_f32_16x16x32_bf16(qf0, k0, s, 0, 0, 0);
        s = __builtin_amdgcn_mfma_f32_16x16x32_bf16(qf1, k1, s, 0, 0, 0);
      }
      if (jbase + jt * 16 + col >= ln) {
#pragma unroll
        for (int r = 0; r < 4; ++r) s[r] = -1e30f;
      }
      sf[jt] = s;
    }
    // ---- online softmax ----
    float mc[4];
#pragma unroll
    for (int r = 0; r < 4; ++r) mc[r] = sf[0][r];
#pragma unroll
    for (int jt = 1; jt < 8; ++jt) {
      if (jt >= jtcp) continue;
#pragma unroll
      for (int r = 0; r < 4; ++r) mc[r] = fmaxf(mc[r], sf[jt][r]);
    }
#pragma unroll
    for (int mask = 1; mask <= 8; mask <<= 1)
#pragma unroll
      for (int r = 0; r < 4; ++r) mc[r] = fmaxf(mc[r], __shfl_xor(mc[r], mask));
    float alpha[4];
#pragma unroll
    for (int r = 0; r < 4; ++r) {
      float mn = fmaxf(m4[r], mc[r]);
      alpha[r] = __expf(m4[r] - mn);
      m4[r] = mn;
    }
    float ls[4] = {0.f, 0.f, 0.f, 0.f};
#pragma unroll
    for (int jt = 0; jt < 8; ++jt) {
      if (jt >= jtcp) continue;
#pragma unroll
      for (int r = 0; r < 4; ++r) {
        float pv = __expf(sf[jt][r] - m4[r]);
        ls[r] += pv;
        Ps[(w * 16 + quad * 4 + r) * 132 + jt * 16 + col] = f32_bf16(pv);
      }
    }
#pragma unroll
    for (int mask = 1; mask <= 8; mask <<= 1)
#pragma unroll
      for (int r = 0; r < 4; ++r) ls[r] += __shfl_xor(ls[r], mask);
#pragma unroll
    for (int r = 0; r < 4; ++r) l4[r] = l4[r] * alpha[r] + ls[r];
#pragma unroll
    for (int nt = 0; nt < 4; ++nt)
#pragma unroll
      for (int r = 0; r < 4; ++r) o[nt][r] *= alpha[r];

    // ---- O += P V ----
#pragma unroll
    for (int kk2 = 0; kk2 < 4; ++kk2) {
      if (kk2 >= (jtcp >> 1)) continue;
      bf16x8 pf = *reinterpret_cast<const bf16x8*>(&Ps[(w * 16 + col) * 132 + kk2 * 32 + quad * 8]);
#pragma unroll
      for (int nt = 0; nt < 4; ++nt) {
        int d = nt * 16 + col;
        int slot = (kk2 * 4 + quad) ^ (d & 15);
        bf16x8 vf = *reinterpret_cast<const bf16x8*>(&Vs[(d * 16 + slot) * 8]);
        o[nt] = __builtin_amdgcn_mfma_f32_16x16x32_bf16(pf, vf, o[nt], 0, 0, 0);
      }
    }
  }

  if (qvalid) {
    float inv[4];
#pragma unroll
    for (int r = 0; r < 4; ++r) inv[r] = 1.f / l4[r];
    const int b = bh >> 4;
#pragma unroll
    for (int nt = 0; nt < 4; ++nt)
#pragma unroll
      for (int r = 0; r < 4; ++r) {
        int ri = qt * 16 + quad * 4 + r;
        if (ri < ln) {
          size_t off = ((size_t)b * Ll + start + ri) * Cc + h * 64 + nt * 16 + col;
          outb[off] = f32_bf16(o[nt][r] * inv[r]);
        }
      }
  }
}

extern "C" void kernel_launch(void* const* d_in, const int* in_sizes, int n_in,
                              void* d_out, int out_size, void* d_ws, size_t ws_size,
                              hipStream_t stream) {
  const float* x     = (const float*)d_in[0];
  const float* wqkv  = (const float*)d_in[2];
  const float* qbias = (const float*)d_in[3];
  const float* vbias = (const float*)d_in[4];
  const float* slog  = (const float*)d_in[5];
  const float* wproj = (const float*)d_in[6];
  const float* pbias = (const float*)d_in[7];
  float* out = (float*)d_out;

  const size_t nX  = (size_t)Bb * Ll * Cc;      // 11,141,120
  const size_t nWq = (size_t)3 * Cc * Cc;       // 3,145,728
  const size_t nWp = (size_t)Cc * Cc;           // 1,048,576
  const size_t nVt = (size_t)Bb * Hh * 64 * LPAD;

  char* p = (char*)d_ws;
  unsigned short* xb     = (unsigned short*)p;  p += nX * 2;
  unsigned short* wqkvb  = (unsigned short*)p;  p += nWq * 2;
  unsigned short* wprojb = (unsigned short*)p;  p += nWp * 2;
  unsigned short* qn     = (unsigned short*)p;  p += nX * 2;
  unsigned short* kn     = (unsigned short*)p;  p += nX * 2;
  unsigned short* vtb    = (unsigned short*)p;  p += nVt * 2;
  unsigned short* attn   = xb;  // reuse: xb dead after gemm_qkv

  conv_kernel<<<(int)(nX / 1024), 256, 0, stream>>>(x, xb, (int)nX);
  conv_kernel<<<(int)(nWq / 1024), 256, 0, stream>>>(wqkv, wqkvb, (int)nWq);
  conv_kernel<<<(int)(nWp / 1024), 256, 0, stream>>>(wproj, wprojb, (int)nWp);

  gemm_qkv<<<dim3(24, 85), 256, 0, stream>>>(xb, wqkvb, qbias, vbias, qn, kn, vtb);
  attn_kernel<<<Bb * Hh * 16, 256, 0, stream>>>(qn, kn, vtb, slog, attn);
  gemm_bt<<<dim3(8, 85), 256, 0, stream>>>(attn, wprojb, pbias, out, 10880, 1024, 1024);
}

// Round 6
// 328.900 us; speedup vs baseline: 1.0510x; 1.0395x over previous
//
#include <hip/hip_runtime.h>

typedef __attribute__((ext_vector_type(8))) short bf16x8;
typedef __attribute__((ext_vector_type(4))) float f32x4;

#define Hh   16
#define Ll   680
#define Cc   1024
#define Bb   16
#define NSEG 10
#define LPAD 720   // padded per-segment V length (each segment start 8-aligned)

__device__ __forceinline__ unsigned short f32_bf16(float f) {
  union { float f; unsigned int u; } x; x.f = f;
  unsigned int r = x.u + 0x7FFFu + ((x.u >> 16) & 1u);   // RNE
  return (unsigned short)(r >> 16);
}
__device__ __forceinline__ float bf16_f32(unsigned short u) {
  union { unsigned int u; float f; } x; x.u = ((unsigned int)u) << 16;
  return x.f;
}

__device__ __forceinline__ void async_copy16(const unsigned short* g, unsigned short* l) {
  __builtin_amdgcn_global_load_lds(
      (const __attribute__((address_space(1))) unsigned int*)g,
      (__attribute__((address_space(3))) unsigned int*)l, 16, 0, 0);
}

// segment tables (patch_nums are compile-time constants)
__device__ __constant__ int c_start2[11] = {0,1,5,14,30,55,91,155,255,424,680};
__device__ __constant__ int c_ps[NSEG]   = {0,8,16,32,48,80,120,184,288,464};
__device__ __constant__ int c_seg[16]    = {0,1,2,3,4,5,6,7,7,8,8,8,9,9,9,9};
__device__ __constant__ int c_tile0[16]  = {0,0,0,0,0,0,0,0,4,0,4,8,0,4,8,12};
__device__ __constant__ int c_len[NSEG]  = {1,4,9,16,25,36,64,100,169,256};

// compile-time l -> padded-l table (kills the per-element segment search)
struct PlTab { unsigned short v[Ll]; };
constexpr PlTab make_pl() {
  PlTab t{};
  int starts[11] = {0,1,5,14,30,55,91,155,255,424,680};
  int ps[10]     = {0,8,16,32,48,80,120,184,288,464};
  for (int s = 0; s < 10; ++s)
    for (int l = starts[s]; l < starts[s + 1]; ++l)
      t.v[l] = (unsigned short)(l - starts[s] + ps[s]);
  return t;
}
__device__ __constant__ PlTab c_plt = make_pl();

// ---------------- elementwise f32 -> bf16 cast ----------------
__global__ __launch_bounds__(256) void conv_kernel(const float* __restrict__ src,
                                                   unsigned short* __restrict__ dst, int n) {
  int i = (blockIdx.x * 256 + threadIdx.x) * 4;
  if (i + 3 < n) {
    float4 v = *reinterpret_cast<const float4*>(src + i);
    ushort4 o;
    o.x = f32_bf16(v.x); o.y = f32_bf16(v.y); o.z = f32_bf16(v.z); o.w = f32_bf16(v.w);
    *reinterpret_cast<ushort4*>(dst + i) = o;
  }
}

// ---------------- QKV GEMM with fused epilogue ----------------
// q -> (B,H,L,D) +bias ; k -> (B,H,L,D) l2-normalized ; v -> (B,H,D,LPAD) +bias, transposed.
__global__ __launch_bounds__(256) void gemm_qkv(const unsigned short* __restrict__ A,
                                                const unsigned short* __restrict__ Bm,
                                                const float* __restrict__ qb,
                                                const float* __restrict__ vb,
                                                unsigned short* __restrict__ qn,
                                                unsigned short* __restrict__ kn,
                                                unsigned short* __restrict__ vtb) {
  constexpr int K = 1024;
  __shared__ __align__(16) unsigned short As[128 * 64];
  __shared__ __align__(16) unsigned short Bs[128 * 64];
  const int t = threadIdx.x;
  const int lane = t & 63, w = t >> 6;
  const int col = lane & 15, quad = lane >> 4;
  const int wm = (w & 1) * 64, wn = (w >> 1) * 64;
  const int m0 = blockIdx.y * 128, n0 = blockIdx.x * 128;

  f32x4 acc[4][4];
#pragma unroll
  for (int i = 0; i < 4; ++i)
#pragma unroll
    for (int j = 0; j < 4; ++j)
#pragma unroll
      for (int r = 0; r < 4; ++r) acc[i][j][r] = 0.f;

  const int cbase = w * 256 + lane;
  for (int k0 = 0; k0 < K; k0 += 64) {
    __syncthreads();
#pragma unroll
    for (int i = 0; i < 4; ++i) {
      int c = cbase + i * 64;
      int r = c >> 3;
      int part = (c & 7) ^ (r & 7);
      async_copy16(A + (size_t)(m0 + r) * K + k0 + part * 8, As + (w * 256 + i * 64) * 8);
      async_copy16(Bm + (size_t)(n0 + r) * K + k0 + part * 8, Bs + (w * 256 + i * 64) * 8);
    }
    __syncthreads();
#pragma unroll
    for (int kk = 0; kk < 64; kk += 32) {
      const int p = (kk >> 3) + quad;
      bf16x8 af[4], bfr[4];
#pragma unroll
      for (int mi = 0; mi < 4; ++mi) {
        int row = wm + mi * 16 + col;
        af[mi] = *reinterpret_cast<const bf16x8*>(&As[(row * 8 + (p ^ (col & 7))) * 8]);
      }
#pragma unroll
      for (int ni = 0; ni < 4; ++ni) {
        int row = wn + ni * 16 + col;
        bfr[ni] = *reinterpret_cast<const bf16x8*>(&Bs[(row * 8 + (p ^ (col & 7))) * 8]);
      }
#pragma unroll
      for (int mi = 0; mi < 4; ++mi)
#pragma unroll
        for (int ni = 0; ni < 4; ++ni)
          acc[mi][ni] = __builtin_amdgcn_mfma_f32_16x16x32_bf16(af[mi], bfr[ni], acc[mi][ni], 0, 0, 0);
    }
  }

  const int nbase = n0 + wn;
  const int field = nbase >> 10;          // wave-uniform
  const int h = (nbase >> 6) & 15;

  if (field < 2) {
    float scl[4][4];
    if (field == 1) {                     // k: per-row 1/||k|| across the 16 col-lanes
#pragma unroll
      for (int mi = 0; mi < 4; ++mi)
#pragma unroll
        for (int r = 0; r < 4; ++r) {
          float s = 0.f;
#pragma unroll
          for (int ni = 0; ni < 4; ++ni) s += acc[mi][ni][r] * acc[mi][ni][r];
          s += __shfl_xor(s, 1); s += __shfl_xor(s, 2);
          s += __shfl_xor(s, 4); s += __shfl_xor(s, 8);
          scl[mi][r] = 1.f / fmaxf(sqrtf(s), 1e-12f);
        }
    }
    unsigned short* dst0 = (field == 0) ? qn : kn;
#pragma unroll
    for (int ni = 0; ni < 4; ++ni) {
      const int d = ni * 16 + col;
      const float bv = (field == 0) ? qb[h * 64 + d] : 0.f;
#pragma unroll
      for (int mi = 0; mi < 4; ++mi)
#pragma unroll
        for (int r = 0; r < 4; ++r) {
          int gm = m0 + wm + mi * 16 + quad * 4 + r;
          int b = gm / 680, l = gm - b * 680;
          float v = (field == 0) ? (acc[mi][ni][r] + bv) : (acc[mi][ni][r] * scl[mi][r]);
          dst0[((size_t)(b * Hh + h) * Ll + l) * 64 + d] = f32_bf16(v);
        }
    }
  } else {                                // v: transposed, segment-padded (table lookup)
#pragma unroll
    for (int mi = 0; mi < 4; ++mi) {
      int pl4[4], bb4[4];
#pragma unroll
      for (int r = 0; r < 4; ++r) {
        int gm = m0 + wm + mi * 16 + quad * 4 + r;
        int b = gm / 680, l = gm - b * 680;
        pl4[r] = c_plt.v[l];
        bb4[r] = b;
      }
#pragma unroll
      for (int ni = 0; ni < 4; ++ni) {
        const int d = ni * 16 + col;
        const float bv = vb[h * 64 + d];
#pragma unroll
        for (int r = 0; r < 4; ++r)
          vtb[((size_t)(bb4[r] * Hh + h) * 64 + d) * LPAD + pl4[r]] =
              f32_bf16(acc[mi][ni][r] + bv);
      }
    }
  }
}

// ---------------- plain B^T GEMM (proj), f32 out ----------------
__global__ __launch_bounds__(256) void gemm_bt(const unsigned short* __restrict__ A,
                                               const unsigned short* __restrict__ Bm,
                                               const float* __restrict__ bias,
                                               float* __restrict__ outp,
                                               int M, int N, int K) {
  __shared__ __align__(16) unsigned short As[128 * 64];
  __shared__ __align__(16) unsigned short Bs[128 * 64];
  const int t = threadIdx.x;
  const int lane = t & 63, w = t >> 6;
  const int col = lane & 15, quad = lane >> 4;
  const int wm = (w & 1) * 64, wn = (w >> 1) * 64;
  const int m0 = blockIdx.y * 128, n0 = blockIdx.x * 128;

  f32x4 acc[4][4];
#pragma unroll
  for (int i = 0; i < 4; ++i)
#pragma unroll
    for (int j = 0; j < 4; ++j)
#pragma unroll
      for (int r = 0; r < 4; ++r) acc[i][j][r] = 0.f;

  const int cbase = w * 256 + lane;
  for (int k0 = 0; k0 < K; k0 += 64) {
    __syncthreads();
#pragma unroll
    for (int i = 0; i < 4; ++i) {
      int c = cbase + i * 64;
      int r = c >> 3;
      int part = (c & 7) ^ (r & 7);
      async_copy16(A + (size_t)(m0 + r) * K + k0 + part * 8, As + (w * 256 + i * 64) * 8);
      async_copy16(Bm + (size_t)(n0 + r) * K + k0 + part * 8, Bs + (w * 256 + i * 64) * 8);
    }
    __syncthreads();
#pragma unroll
    for (int kk = 0; kk < 64; kk += 32) {
      const int p = (kk >> 3) + quad;
      bf16x8 af[4], bfr[4];
#pragma unroll
      for (int mi = 0; mi < 4; ++mi) {
        int row = wm + mi * 16 + col;
        af[mi] = *reinterpret_cast<const bf16x8*>(&As[(row * 8 + (p ^ (col & 7))) * 8]);
      }
#pragma unroll
      for (int ni = 0; ni < 4; ++ni) {
        int row = wn + ni * 16 + col;
        bfr[ni] = *reinterpret_cast<const bf16x8*>(&Bs[(row * 8 + (p ^ (col & 7))) * 8]);
      }
#pragma unroll
      for (int mi = 0; mi < 4; ++mi)
#pragma unroll
        for (int ni = 0; ni < 4; ++ni)
          acc[mi][ni] = __builtin_amdgcn_mfma_f32_16x16x32_bf16(af[mi], bfr[ni], acc[mi][ni], 0, 0, 0);
    }
  }
#pragma unroll
  for (int mi = 0; mi < 4; ++mi)
#pragma unroll
    for (int ni = 0; ni < 4; ++ni) {
      int gn = n0 + wn + ni * 16 + col;
      float bv = bias[gn];
#pragma unroll
      for (int r = 0; r < 4; ++r) {
        int gm = m0 + wm + mi * 16 + quad * 4 + r;
        outp[(size_t)gm * N + gn] = acc[mi][ni][r] + bv;
      }
    }
}

// ---------------- attention v5: sized staging + XCD-grouped slots ----------------
// blockIdx = wi*256 + bh  ->  all 16 slots of one (b,h) share blockIdx%8 (same XCD L2).
// Staging sized to the segment: K stages jtc*16 rows; V stages jtcp*2 j-chunks per d.
__global__ __launch_bounds__(256) void attn_kernel(const unsigned short* __restrict__ qn,
                                                   const unsigned short* __restrict__ kn,
                                                   const unsigned short* __restrict__ vtb,
                                                   const float* __restrict__ slog,
                                                   unsigned short* __restrict__ outb) {
  __shared__ __align__(16) unsigned short Ks[128 * 64];   // chunk(row,cc) at row*8 + (cc^(row&7))
  __shared__ __align__(16) unsigned short Vs[64 * 128];   // chunk(d,jc)  at d*16 + (jc^(d&15))
  __shared__ __align__(16) unsigned short Ps[4 * 16 * 132];

  const int t = threadIdx.x;
  const int lane = t & 63, w = t >> 6;
  const int col = lane & 15, quad = lane >> 4;
  const int wi = blockIdx.x >> 8, bh = blockIdx.x & 255;
  const int h = bh & 15;
  const int seg = c_seg[wi];
  const int start = c_start2[seg], ln = c_len[seg], ps = c_ps[seg];
  const int njt = (ln + 15) >> 4;
  const int nchunk = (njt + 7) >> 3;
  const int qt = c_tile0[wi] + w;
  const bool qvalid = qt < njt;
  const float smul = __expf(fminf(slog[h], 4.6051701859880914f));

  // ---- Q fragment + in-register l2norm*scale ----
  const int qi = qt * 16 + col;
  const unsigned short* qrow = qn + ((size_t)bh * Ll + start + qi) * 64;
  bf16x8 qf0 = *reinterpret_cast<const bf16x8*>(qrow + quad * 8);
  bf16x8 qf1 = *reinterpret_cast<const bf16x8*>(qrow + 32 + quad * 8);
  {
    float ss = 0.f;
#pragma unroll
    for (int e = 0; e < 8; ++e) {
      float f0 = bf16_f32((unsigned short)qf0[e]), f1 = bf16_f32((unsigned short)qf1[e]);
      ss += f0 * f0 + f1 * f1;
    }
    ss += __shfl_xor(ss, 16);
    ss += __shfl_xor(ss, 32);
    const float qsc = smul / fmaxf(sqrtf(ss), 1e-12f);
#pragma unroll
    for (int e = 0; e < 8; ++e) {
      qf0[e] = (short)f32_bf16(bf16_f32((unsigned short)qf0[e]) * qsc);
      qf1[e] = (short)f32_bf16(bf16_f32((unsigned short)qf1[e]) * qsc);
    }
  }

  f32x4 o[4];
#pragma unroll
  for (int nt = 0; nt < 4; ++nt)
#pragma unroll
    for (int r = 0; r < 4; ++r) o[nt][r] = 0.f;
  float m4[4] = {-1e30f, -1e30f, -1e30f, -1e30f};
  float l4[4] = {0.f, 0.f, 0.f, 0.f};

  const int jc_t = (t & 15) ^ (t >> 4);   // thread-fixed V j-chunk

  for (int ch = 0; ch < nchunk; ++ch) {
    const int jbase = ch * 128;
    const int jtc = (njt - ch * 8 > 8) ? 8 : (njt - ch * 8);
    const int jtcp = (jtc + 1) & ~1;
    const int rowsK = jtc * 16;
    const int jcmax = jtcp * 2;
    __syncthreads();   // previous chunk's LDS reads done

    // ---- stage K rows (rowsK x 64d): chunk grid 128x8, rows >= rowsK skipped ----
#pragma unroll
    for (int i = 0; i < 4; ++i) {
      int c = i * 256 + w * 64 + lane;
      int jr = c >> 3;
      if (jr < rowsK) {
        int cc = (c & 7) ^ (jr & 7);
        async_copy16(kn + ((size_t)bh * Ll + start + jbase + jr) * 64 + cc * 8,
                     Ks + (i * 256 + w * 64) * 8);
      }
    }
    // ---- stage V^T (64d x jcmax*8 j): chunk grid 64x16, jc >= jcmax skipped ----
    if (jc_t < jcmax) {
#pragma unroll
      for (int i = 0; i < 4; ++i) {
        int d = i * 16 + (t >> 4);
        async_copy16(vtb + ((size_t)bh * 64 + d) * LPAD + ps + jbase + jc_t * 8,
                     Vs + (i * 256 + w * 64) * 8);
      }
    }
    __syncthreads();

    // ---- S = Q K^T ----
    f32x4 sf[8];
#pragma unroll
    for (int jt = 0; jt < 8; ++jt) {
      if (jt >= jtcp) continue;
      f32x4 s;
#pragma unroll
      for (int r = 0; r < 4; ++r) s[r] = 0.f;
      if (jt < jtc) {
        int jrow = jt * 16 + col;
        bf16x8 k0 = *reinterpret_cast<const bf16x8*>(&Ks[(jrow * 8 + (quad ^ (jrow & 7))) * 8]);
        bf16x8 k1 = *reinterpret_cast<const bf16x8*>(&Ks[(jrow * 8 + ((4 + quad) ^ (jrow & 7))) * 8]);
        s = __builtin_amdgcn_mfma_f32_16x16x32_bf16(qf0, k0, s, 0, 0, 0);
        s = __builtin_amdgcn_mfma_f32_16x16x32_bf16(qf1, k1, s, 0, 0, 0);
      }
      if (jbase + jt * 16 + col >= ln) {
#pragma unroll
        for (int r = 0; r < 4; ++r) s[r] = -1e30f;
      }
      sf[jt] = s;
    }
    // ---- online softmax ----
    float mc[4];
#pragma unroll
    for (int r = 0; r < 4; ++r) mc[r] = sf[0][r];
#pragma unroll
    for (int jt = 1; jt < 8; ++jt) {
      if (jt >= jtcp) continue;
#pragma unroll
      for (int r = 0; r < 4; ++r) mc[r] = fmaxf(mc[r], sf[jt][r]);
    }
#pragma unroll
    for (int mask = 1; mask <= 8; mask <<= 1)
#pragma unroll
      for (int r = 0; r < 4; ++r) mc[r] = fmaxf(mc[r], __shfl_xor(mc[r], mask));
    float alpha[4];
#pragma unroll
    for (int r = 0; r < 4; ++r) {
      float mn = fmaxf(m4[r], mc[r]);
      alpha[r] = __expf(m4[r] - mn);
      m4[r] = mn;
    }
    float ls[4] = {0.f, 0.f, 0.f, 0.f};
#pragma unroll
    for (int jt = 0; jt < 8; ++jt) {
      if (jt >= jtcp) continue;
#pragma unroll
      for (int r = 0; r < 4; ++r) {
        float pv = __expf(sf[jt][r] - m4[r]);
        ls[r] += pv;
        Ps[(w * 16 + quad * 4 + r) * 132 + jt * 16 + col] = f32_bf16(pv);
      }
    }
#pragma unroll
    for (int mask = 1; mask <= 8; mask <<= 1)
#pragma unroll
      for (int r = 0; r < 4; ++r) ls[r] += __shfl_xor(ls[r], mask);
#pragma unroll
    for (int r = 0; r < 4; ++r) l4[r] = l4[r] * alpha[r] + ls[r];
#pragma unroll
    for (int nt = 0; nt < 4; ++nt)
#pragma unroll
      for (int r = 0; r < 4; ++r) o[nt][r] *= alpha[r];

    // ---- O += P V ----
#pragma unroll
    for (int kk2 = 0; kk2 < 4; ++kk2) {
      if (kk2 >= (jtcp >> 1)) continue;
      bf16x8 pf = *reinterpret_cast<const bf16x8*>(&Ps[(w * 16 + col) * 132 + kk2 * 32 + quad * 8]);
#pragma unroll
      for (int nt = 0; nt < 4; ++nt) {
        int d = nt * 16 + col;
        int slot = (kk2 * 4 + quad) ^ (d & 15);
        bf16x8 vf = *reinterpret_cast<const bf16x8*>(&Vs[(d * 16 + slot) * 8]);
        o[nt] = __builtin_amdgcn_mfma_f32_16x16x32_bf16(pf, vf, o[nt], 0, 0, 0);
      }
    }
  }

  if (qvalid) {
    float inv[4];
#pragma unroll
    for (int r = 0; r < 4; ++r) inv[r] = 1.f / l4[r];
    const int b = bh >> 4;
#pragma unroll
    for (int nt = 0; nt < 4; ++nt)
#pragma unroll
      for (int r = 0; r < 4; ++r) {
        int ri = qt * 16 + quad * 4 + r;
        if (ri < ln) {
          size_t off = ((size_t)b * Ll + start + ri) * Cc + h * 64 + nt * 16 + col;
          outb[off] = f32_bf16(o[nt][r] * inv[r]);
        }
      }
  }
}

extern "C" void kernel_launch(void* const* d_in, const int* in_sizes, int n_in,
                              void* d_out, int out_size, void* d_ws, size_t ws_size,
                              hipStream_t stream) {
  const float* x     = (const float*)d_in[0];
  const float* wqkv  = (const float*)d_in[2];
  const float* qbias = (const float*)d_in[3];
  const float* vbias = (const float*)d_in[4];
  const float* slog  = (const float*)d_in[5];
  const float* wproj = (const float*)d_in[6];
  const float* pbias = (const float*)d_in[7];
  float* out = (float*)d_out;

  const size_t nX  = (size_t)Bb * Ll * Cc;      // 11,141,120
  const size_t nWq = (size_t)3 * Cc * Cc;       // 3,145,728
  const size_t nWp = (size_t)Cc * Cc;           // 1,048,576
  const size_t nVt = (size_t)Bb * Hh * 64 * LPAD;

  char* p = (char*)d_ws;
  unsigned short* xb     = (unsigned short*)p;  p += nX * 2;
  unsigned short* wqkvb  = (unsigned short*)p;  p += nWq * 2;
  unsigned short* wprojb = (unsigned short*)p;  p += nWp * 2;
  unsigned short* qn     = (unsigned short*)p;  p += nX * 2;
  unsigned short* kn     = (unsigned short*)p;  p += nX * 2;
  unsigned short* vtb    = (unsigned short*)p;  p += nVt * 2;
  unsigned short* attn   = xb;  // reuse: xb dead after gemm_qkv

  conv_kernel<<<(int)(nX / 1024), 256, 0, stream>>>(x, xb, (int)nX);
  conv_kernel<<<(int)(nWq / 1024), 256, 0, stream>>>(wqkv, wqkvb, (int)nWq);
  conv_kernel<<<(int)(nWp / 1024), 256, 0, stream>>>(wproj, wprojb, (int)nWp);

  gemm_qkv<<<dim3(24, 85), 256, 0, stream>>>(xb, wqkvb, qbias, vbias, qn, kn, vtb);
  attn_kernel<<<Bb * Hh * 16, 256, 0, stream>>>(qn, kn, vtb, slog, attn);
  gemm_bt<<<dim3(8, 85), 256, 0, stream>>>(attn, wprojb, pbias, out, 10880, 1024, 1024);
}